// Round 12
// baseline (912.307 us; speedup 1.0000x reference)
//
#include <hip/hip_runtime.h>
#include <math.h>

#define N_NODES 50000
#define N_EDGES 800000
#define IN_DIMC 128
#define D1 256      // heads*hid (layer-1 output width, also skip width)
#define D3 768      // q|k|v concat width
#define D2ALL 40    // layer-2 q|k|v|skip concat width

// ---------------- diagnostic fallback ----------------
__global__ void k_zero(float* __restrict__ out, int n){
  int i = blockIdx.x*blockDim.x + threadIdx.x;
  if (i < n) out[i] = 0.f;
}

// ---------------- edge decode: robust to int32 / int64 edge_index ----------------
__global__ void k_edges(const int* __restrict__ w, int* __restrict__ s0, int* __restrict__ d0){
  __shared__ int is64_s;
  if (threadIdx.x == 0){
    int acc = 0;
    #pragma unroll
    for (int j = 0; j < 17; j++) acc |= w[2*j+1];   // int64 hi-words are 0 (ids<50000)
    is64_s = (acc == 0);
  }
  __syncthreads();
  bool is64 = is64_s;
  int e = blockIdx.x*blockDim.x + threadIdx.x;
  if (e < N_EDGES){
    if (is64){ s0[e] = w[2*e];  d0[e] = w[2*(N_EDGES + e)]; }
    else     { s0[e] = w[e];    d0[e] = w[N_EDGES + e];     }
  }
}

// ---------------- CSR build ----------------
__global__ void k_count(const int* __restrict__ d0, int* __restrict__ deg){
  int e = blockIdx.x*blockDim.x + threadIdx.x;
  if (e < N_EDGES) atomicAdd(&deg[d0[e]], 1);
}

__global__ __launch_bounds__(1024) void k_scan(const int* __restrict__ deg,
                                               int* __restrict__ rowptr,
                                               int* __restrict__ cursor){
  __shared__ int wsum[16];
  __shared__ int carry_s;
  int t = threadIdx.x;
  int w = t >> 6, lane = t & 63;
  if (t == 0){ carry_s = 0; rowptr[0] = 0; }
  __syncthreads();
  for (int base = 0; base < N_NODES; base += 1024){
    int i = base + t;
    int v = (i < N_NODES) ? deg[i] : 0;
    int s = v;
    #pragma unroll
    for (int off = 1; off < 64; off <<= 1){
      int u = __shfl_up(s, off);
      if (lane >= off) s += u;
    }
    if (lane == 63) wsum[w] = s;
    __syncthreads();
    if (w == 0 && lane < 16){
      int ws = wsum[lane];
      #pragma unroll
      for (int off = 1; off < 16; off <<= 1){
        int u = __shfl_up(ws, off);
        if (lane >= off) ws += u;
      }
      wsum[lane] = ws;
    }
    __syncthreads();
    int waveoff = (w == 0) ? 0 : wsum[w-1];
    int incl = carry_s + waveoff + s;
    if (i < N_NODES){
      rowptr[i+1] = incl;
      cursor[i]   = incl - v;
    }
    __syncthreads();
    if (t == 1023) carry_s = incl;
    __syncthreads();
  }
}

__global__ void k_scatter(const int* __restrict__ s0, const int* __restrict__ d0,
                          int* __restrict__ cursor, int* __restrict__ esrc){
  int e = blockIdx.x*blockDim.x + threadIdx.x;
  if (e < N_EDGES){
    int slot = atomicAdd(&cursor[d0[e]], 1);
    esrc[slot] = s0[e];
  }
}

// ---------------- linear: x[N,128] @ w[128,256] col-tiles; 128x128 block tile ----
// grid (8, nb): bx 0..5 -> q|k|v into qkv1 (stride 768), bx 6..7 -> skip into hbuf
// BK=32, 256 threads as 16x16, micro-tile 8x8: 16 FMA per ds_read_b128.
__global__ __launch_bounds__(256) void k_lin(const float* __restrict__ x,
        const float* __restrict__ wq, const float* __restrict__ wk,
        const float* __restrict__ wv, const float* __restrict__ wsk,
        const float* __restrict__ bq, const float* __restrict__ bk,
        const float* __restrict__ bv, const float* __restrict__ bs,
        float* __restrict__ oqkv, float* __restrict__ oskip){
  __shared__ float xs[128][36];     // row stride 144B (16B-aligned)
  __shared__ float wls[32][128];
  int t  = threadIdx.x;
  int ty = t >> 4, tx = t & 15;
  int n0  = blockIdx.y * 128;
  int bx  = blockIdx.x;
  int sel  = bx >> 1;                  // 0..3 -> q,k,v,skip
  int wcol = (bx & 1) * 128;
  const float* wptr = sel==0 ? wq : sel==1 ? wk : sel==2 ? wv : wsk;
  const float* bptr = sel==0 ? bq : sel==1 ? bk : sel==2 ? bv : bs;
  float* out  = (sel < 3) ? oqkv : oskip;
  int ostride = (sel < 3) ? D3 : D1;
  int col0    = (sel < 3) ? sel*256 + wcol : wcol;

  float acc[8][8];
  #pragma unroll
  for (int i=0;i<8;i++)
    #pragma unroll
    for (int j=0;j<8;j++) acc[i][j] = 0.f;

  for (int k0 = 0; k0 < IN_DIMC; k0 += 32){
    #pragma unroll
    for (int q = 0; q < 4; q++){            // x tile 128x32
      int L = (q*256 + t)*4;
      int row = L >> 5, col = L & 31;
      int gr = n0 + row;
      float4 vv = make_float4(0.f,0.f,0.f,0.f);
      if (gr < N_NODES) vv = *(const float4*)(x + (size_t)gr*IN_DIMC + k0 + col);
      *(float4*)&xs[row][col] = vv;
    }
    #pragma unroll
    for (int q = 0; q < 4; q++){            // w tile 32x128
      int L = (q*256 + t)*4;
      int row = L >> 7, col = L & 127;
      float4 vv = *(const float4*)(wptr + (size_t)(k0+row)*256 + wcol + col);
      *(float4*)&wls[row][col] = vv;
    }
    __syncthreads();
    for (int kk = 0; kk < 32; kk += 4){
      float4 aq[8];
      #pragma unroll
      for (int i=0;i<8;i++) aq[i] = *(const float4*)&xs[ty*8+i][kk];
      #pragma unroll
      for (int u=0;u<4;u++){
        float4 b0v = *(const float4*)&wls[kk+u][tx*4];       // 2-way banked = free
        float4 b1v = *(const float4*)&wls[kk+u][64 + tx*4];
        #pragma unroll
        for (int i=0;i<8;i++){
          float a = ((const float*)&aq[i])[u];
          acc[i][0] = fmaf(a,b0v.x,acc[i][0]);
          acc[i][1] = fmaf(a,b0v.y,acc[i][1]);
          acc[i][2] = fmaf(a,b0v.z,acc[i][2]);
          acc[i][3] = fmaf(a,b0v.w,acc[i][3]);
          acc[i][4] = fmaf(a,b1v.x,acc[i][4]);
          acc[i][5] = fmaf(a,b1v.y,acc[i][5]);
          acc[i][6] = fmaf(a,b1v.z,acc[i][6]);
          acc[i][7] = fmaf(a,b1v.w,acc[i][7]);
        }
      }
    }
    __syncthreads();
  }
  #pragma unroll
  for (int i=0;i<8;i++){
    int row = n0 + ty*8 + i;
    if (row < N_NODES){
      float4 o0, o1;
      o0.x = acc[i][0] + bptr[wcol + tx*4 + 0];
      o0.y = acc[i][1] + bptr[wcol + tx*4 + 1];
      o0.z = acc[i][2] + bptr[wcol + tx*4 + 2];
      o0.w = acc[i][3] + bptr[wcol + tx*4 + 3];
      o1.x = acc[i][4] + bptr[wcol + 64 + tx*4 + 0];
      o1.y = acc[i][5] + bptr[wcol + 64 + tx*4 + 1];
      o1.z = acc[i][6] + bptr[wcol + 64 + tx*4 + 2];
      o1.w = acc[i][7] + bptr[wcol + 64 + tx*4 + 3];
      *(float4*)(out + (size_t)row*ostride + col0 + tx*4)      = o0;
      *(float4*)(out + (size_t)row*ostride + col0 + 64 + tx*4) = o1;
    }
  }
}

// ---------------- layer-1 fused attention: one wave per node, 2-edge unroll ----
__global__ __launch_bounds__(256) void k_attn1(const float* __restrict__ qkv1,
      const int* __restrict__ rowptr, const int* __restrict__ esrc,
      float* __restrict__ hbuf){
  int wid  = threadIdx.x >> 6;
  int lane = threadIdx.x & 63;
  int n = blockIdx.x*4 + wid;
  if (n >= N_NODES) return;
  int beg = rowptr[n], end = rowptr[n+1];

  float4 q = *(const float4*)(qkv1 + (size_t)n*D3 + lane*4);
  const float sc = 0.17677669529663687f;     // 1/sqrt(32), folded into q
  q.x*=sc; q.y*=sc; q.z*=sc; q.w*=sc;

  float m = -INFINITY, s = 0.f;
  float4 acc = make_float4(0.f,0.f,0.f,0.f);
  int i = beg;
  for (; i + 1 < end; i += 2){               // 2 edges/iter: 4 loads in flight
    int sA = esrc[i], sB = esrc[i+1];
    float4 ka = *(const float4*)(qkv1 + (size_t)sA*D3 + 256 + lane*4);
    float4 va = *(const float4*)(qkv1 + (size_t)sA*D3 + 512 + lane*4);
    float4 kb = *(const float4*)(qkv1 + (size_t)sB*D3 + 256 + lane*4);
    float4 vb = *(const float4*)(qkv1 + (size_t)sB*D3 + 512 + lane*4);
    float pa = q.x*ka.x + q.y*ka.y + q.z*ka.z + q.w*ka.w;
    float pb = q.x*kb.x + q.y*kb.y + q.z*kb.z + q.w*kb.w;
    pa += __shfl_xor(pa, 1);  pb += __shfl_xor(pb, 1);
    pa += __shfl_xor(pa, 2);  pb += __shfl_xor(pb, 2);
    pa += __shfl_xor(pa, 4);  pb += __shfl_xor(pb, 4);
    float mn = fmaxf(m, fmaxf(pa, pb));
    float c  = __expf(m - mn);
    float wa = __expf(pa - mn);
    float wb = __expf(pb - mn);
    s = s*c + wa + wb;
    acc.x = acc.x*c + wa*va.x + wb*vb.x;
    acc.y = acc.y*c + wa*va.y + wb*vb.y;
    acc.z = acc.z*c + wa*va.z + wb*vb.z;
    acc.w = acc.w*c + wa*va.w + wb*vb.w;
    m = mn;
  }
  if (i < end){                              // tail edge
    int sA = esrc[i];
    float4 ka = *(const float4*)(qkv1 + (size_t)sA*D3 + 256 + lane*4);
    float4 va = *(const float4*)(qkv1 + (size_t)sA*D3 + 512 + lane*4);
    float pa = q.x*ka.x + q.y*ka.y + q.z*ka.z + q.w*ka.w;
    pa += __shfl_xor(pa, 1);
    pa += __shfl_xor(pa, 2);
    pa += __shfl_xor(pa, 4);
    float mn = fmaxf(m, pa);
    float c  = __expf(m - mn);
    float wa = __expf(pa - mn);
    s = s*c + wa;
    acc.x = acc.x*c + wa*va.x;
    acc.y = acc.y*c + wa*va.y;
    acc.z = acc.z*c + wa*va.z;
    acc.w = acc.w*c + wa*va.w;
  }
  float inv = 1.f/(s + 1e-16f);
  size_t o = (size_t)n*D1 + lane*4;
  float4 sk = *(const float4*)(hbuf + o);    // skip term (pre-stored)
  float4 r;
  r.x = acc.x*inv + sk.x;
  r.y = acc.y*inv + sk.y;
  r.z = acc.z*inv + sk.z;
  r.w = acc.w*inv + sk.w;
  r.x = r.x > 0.f ? r.x : expm1f(r.x);       // ELU
  r.y = r.y > 0.f ? r.y : expm1f(r.y);
  r.z = r.z > 0.f ? r.z : expm1f(r.z);
  r.w = r.w > 0.f ? r.w : expm1f(r.w);
  *(float4*)(hbuf + o) = r;
}

// ---------------- layer-2 GEMM: h[N,256] @ [w2q|w2k|w2v|w2s][256,10] ----------------
__global__ __launch_bounds__(256) void k_gemm2(const float* __restrict__ hin,
     const float* __restrict__ wq, const float* __restrict__ wk,
     const float* __restrict__ wv, const float* __restrict__ wsk,
     const float* __restrict__ bq, const float* __restrict__ bk,
     const float* __restrict__ bv, const float* __restrict__ bs,
     float* __restrict__ out){
  __shared__ float hs[64][68];
  __shared__ float wsm[64][40];
  int t = threadIdx.x;
  int r = t >> 2, g = t & 3;
  int n0 = blockIdx.x * 64;
  const float* bsel = g==0 ? bq : g==1 ? bk : g==2 ? bv : bs;
  float acc[10];
  #pragma unroll
  for (int j=0;j<10;j++) acc[j] = 0.f;

  for (int k0 = 0; k0 < D1; k0 += 64){
    #pragma unroll
    for (int q = 0; q < 4; q++){
      int L = (q*256 + t)*4;
      int row = L >> 6, col = L & 63;
      int gr = n0 + row;
      float4 vv = make_float4(0.f,0.f,0.f,0.f);
      if (gr < N_NODES) vv = *(const float4*)(hin + (size_t)gr*D1 + k0 + col);
      *(float4*)&hs[row][col] = vv;
    }
    for (int L = t; L < 64*40; L += 256){
      int row = L/40, cc = L%40;
      int sl = cc/10;
      const float* p = sl==0 ? wq : sl==1 ? wk : sl==2 ? wv : wsk;
      wsm[row][cc] = p[(size_t)(k0+row)*10 + (cc - sl*10)];
    }
    __syncthreads();
    for (int kk = 0; kk < 64; kk++){
      float a = hs[r][kk];
      #pragma unroll
      for (int j=0;j<10;j++) acc[j] = fmaf(a, wsm[kk][g*10+j], acc[j]);
    }
    __syncthreads();
  }
  int gr = n0 + r;
  if (gr < N_NODES){
    #pragma unroll
    for (int j=0;j<10;j++)
      out[(size_t)gr*D2ALL + g*10 + j] = acc[j] + bsel[j];
  }
}

// ---------------- layer-2 fused attention: ONE WAVE PER NODE ----------------
// lane l handles edge beg+l (64 edges in parallel); wave-reduce max/sum/acc
// with online rescale per 64-edge chunk. No l2 buffer needed.
__global__ __launch_bounds__(256) void k_agg2(const float* __restrict__ qkvs2,
    const int* __restrict__ rowptr, const int* __restrict__ esrc,
    float* __restrict__ out){
  int wid  = threadIdx.x >> 6;
  int lane = threadIdx.x & 63;
  int n = blockIdx.x*4 + wid;
  if (n >= N_NODES) return;
  int beg = rowptr[n], end = rowptr[n+1];

  float qv[10];
  #pragma unroll
  for (int j=0;j<10;j++) qv[j] = qkvs2[(size_t)n*D2ALL + j];   // uniform/broadcast

  float m = -INFINITY, s = 0.f;
  float acc[10];
  #pragma unroll
  for (int j=0;j<10;j++) acc[j] = 0.f;

  for (int base = beg; base < end; base += 64){
    int i  = base + lane;
    int ic = i < end ? i : end-1;          // clamp: duplicate loads, masked below
    int src = esrc[ic];
    const float* kp = qkvs2 + (size_t)src*D2ALL + 10;
    const float* vp = qkvs2 + (size_t)src*D2ALL + 20;
    float d = 0.f;
    #pragma unroll
    for (int j=0;j<10;j++) d = fmaf(qv[j], kp[j], d);
    float sd = (i < end) ? d * 0.31622776601683794f : -INFINITY;  // 1/sqrt(10)
    float vv[10];
    #pragma unroll
    for (int j=0;j<10;j++) vv[j] = vp[j];
    // wave max
    float cm = sd;
    #pragma unroll
    for (int off = 1; off < 64; off <<= 1) cm = fmaxf(cm, __shfl_xor(cm, off));
    float mn = fmaxf(m, cm);
    float c  = __expf(m - mn);             // 0 on first chunk (m=-inf)
    float w  = (i < end) ? __expf(sd - mn) : 0.f;
    float ws = w;
    #pragma unroll
    for (int off = 1; off < 64; off <<= 1) ws += __shfl_xor(ws, off);
    s = s*c + ws;
    #pragma unroll
    for (int j=0;j<10;j++){
      float aj = w * vv[j];
      #pragma unroll
      for (int off = 1; off < 64; off <<= 1) aj += __shfl_xor(aj, off);
      acc[j] = acc[j]*c + aj;
    }
    m = mn;
  }
  if (lane == 0){
    float inv = 1.f/(s + 1e-16f);
    const float* sp = qkvs2 + (size_t)n*D2ALL + 30;
    #pragma unroll
    for (int j=0;j<10;j++) out[(size_t)n*10 + j] = acc[j]*inv + sp[j];
  }
}

static inline size_t align256(size_t x){ return (x + 255) & ~(size_t)255; }

extern "C" void kernel_launch(void* const* d_in, const int* in_sizes, int n_in,
                              void* d_out, int out_size, void* d_ws, size_t ws_size,
                              hipStream_t stream) {
  const float* x   = (const float*)d_in[0];
  const int*   eiw = (const int*)d_in[1];
  const float* w1q=(const float*)d_in[2],  *b1q=(const float*)d_in[3];
  const float* w1k=(const float*)d_in[4],  *b1k=(const float*)d_in[5];
  const float* w1v=(const float*)d_in[6],  *b1v=(const float*)d_in[7];
  const float* w1s=(const float*)d_in[8],  *b1s=(const float*)d_in[9];
  const float* w2q=(const float*)d_in[10], *b2q=(const float*)d_in[11];
  const float* w2k=(const float*)d_in[12], *b2k=(const float*)d_in[13];
  const float* w2v=(const float*)d_in[14], *b2v=(const float*)d_in[15];
  const float* w2s=(const float*)d_in[16], *b2s=(const float*)d_in[17];

  // ---- workspace layout (aliased; peak 208.2 MB) ----
  const size_t offRow  = 0;
  const size_t offEsrc = align256((size_t)(N_NODES+1)*4);          // rowptr
  const size_t offHbuf = offEsrc + align256((size_t)N_EDGES*4);    // esrc
  const size_t offR    = offHbuf + (size_t)N_NODES*D1*4;           // hbuf
  const size_t REQ     = offR    + (size_t)N_NODES*D3*4;           // qkv region

  if (ws_size < REQ){   // diagnostic: clean wrong-answer instead of OOB crash
    k_zero<<<(out_size+255)/256, 256, 0, stream>>>((float*)d_out, out_size);
    return;
  }

  char* base = (char*)d_ws;
  int*   rowptr = (int*)(base + offRow);
  int*   esrc   = (int*)(base + offEsrc);
  float* hbuf   = (float*)(base + offHbuf);
  float* qkv1   = (float*)(base + offR);
  // CSR temps alias the qkv region (dead before k_lin writes it)
  int*   deg    = (int*)(base + offR);
  int*   cursor = (int*)(base + offR + align256((size_t)N_NODES*4));
  int*   s0     = (int*)(base + offR + 2*align256((size_t)N_NODES*4));
  int*   d0     = (int*)(base + offR + 2*align256((size_t)N_NODES*4) + align256((size_t)N_EDGES*4));
  // layer-2 buffer aliases the qkv region (qkv dead after k_attn1)
  float* qkvs2  = (float*)(base + offR);

  k_edges  <<<(N_EDGES+255)/256, 256, 0, stream>>>(eiw, s0, d0);
  hipMemsetAsync(deg, 0, (size_t)N_NODES*4, stream);
  k_count  <<<(N_EDGES+255)/256, 256, 0, stream>>>(d0, deg);
  k_scan   <<<1, 1024, 0, stream>>>(deg, rowptr, cursor);
  k_scatter<<<(N_EDGES+255)/256, 256, 0, stream>>>(s0, d0, cursor, esrc);

  k_lin<<<dim3(8, (N_NODES+127)/128), 256, 0, stream>>>(
      x, w1q,w1k,w1v,w1s, b1q,b1k,b1v,b1s, qkv1, hbuf);   // q|k|v + skip
  k_attn1<<<(N_NODES+3)/4, 256, 0, stream>>>(qkv1, rowptr, esrc, hbuf);

  k_gemm2<<<(N_NODES+63)/64, 256, 0, stream>>>(
      hbuf, w2q,w2k,w2v,w2s, b2q,b2k,b2v,b2s, qkvs2);
  k_agg2<<<(N_NODES+3)/4, 256, 0, stream>>>(qkvs2, rowptr, esrc, (float*)d_out);
}

// Round 13
// 775.399 us; speedup vs baseline: 1.1766x; 1.1766x over previous
//
#include <hip/hip_runtime.h>
#include <hip/hip_fp16.h>
#include <math.h>

#define N_NODES 50000
#define N_EDGES 800000
#define IN_DIMC 128
#define D1 256      // heads*hid (layer-1 output width, also skip width)
#define DQV 512     // q|v concat width (fp32); k lives separately in fp16
#define D2ALL 40    // layer-2 q|k|v|skip concat width
#define SCHUNK 1024
#define NCHUNK ((N_NODES + SCHUNK - 1) / SCHUNK)   // 49

// ---------------- diagnostic fallback ----------------
__global__ void k_zero(float* __restrict__ out, int n){
  int i = blockIdx.x*blockDim.x + threadIdx.x;
  if (i < n) out[i] = 0.f;
}

// ---------------- edge decode + degree count (fused) ----------------
__global__ void k_edges(const int* __restrict__ w, int* __restrict__ s0,
                        int* __restrict__ d0, int* __restrict__ deg){
  __shared__ int is64_s;
  if (threadIdx.x == 0){
    int acc = 0;
    #pragma unroll
    for (int j = 0; j < 17; j++) acc |= w[2*j+1];   // int64 hi-words are 0 (ids<50000)
    is64_s = (acc == 0);
  }
  __syncthreads();
  bool is64 = is64_s;
  int e = blockIdx.x*blockDim.x + threadIdx.x;
  if (e < N_EDGES){
    int s, d;
    if (is64){ s = w[2*e];  d = w[2*(N_EDGES + e)]; }
    else     { s = w[e];    d = w[N_EDGES + e];     }
    s0[e] = s;
    d0[e] = d;
    atomicAdd(&deg[d], 1);
  }
}

// ---------------- parallel 3-phase scan over deg[50000] ----------------
__global__ __launch_bounds__(1024) void k_scanA(const int* __restrict__ deg,
      int* __restrict__ tscan, int* __restrict__ bsum){
  __shared__ int wsum[16];
  int b = blockIdx.x, t = threadIdx.x;
  int w = t >> 6, lane = t & 63;
  int i = b*SCHUNK + t;
  int v = (i < N_NODES) ? deg[i] : 0;
  int s = v;
  #pragma unroll
  for (int off = 1; off < 64; off <<= 1){
    int u = __shfl_up(s, off);
    if (lane >= off) s += u;
  }
  if (lane == 63) wsum[w] = s;
  __syncthreads();
  if (w == 0 && lane < 16){
    int ws = wsum[lane];
    #pragma unroll
    for (int off = 1; off < 16; off <<= 1){
      int u = __shfl_up(ws, off);
      if (lane >= off) ws += u;
    }
    wsum[lane] = ws;
  }
  __syncthreads();
  int incl = ((w == 0) ? 0 : wsum[w-1]) + s;   // block-inclusive prefix
  if (i < N_NODES) tscan[i] = incl;
  if (t == 1023) bsum[b] = incl;               // block total
}

__global__ void k_scanB(const int* __restrict__ bsum, int* __restrict__ boff){
  int lane = threadIdx.x;                      // 64 threads, 1 block
  int v = (lane < NCHUNK) ? bsum[lane] : 0;
  int s = v;
  #pragma unroll
  for (int off = 1; off < 64; off <<= 1){
    int u = __shfl_up(s, off);
    if (lane >= off) s += u;
  }
  if (lane < NCHUNK) boff[lane] = s - v;       // exclusive block offset
}

__global__ __launch_bounds__(1024) void k_scanC(const int* __restrict__ deg,
      const int* __restrict__ tscan, const int* __restrict__ boff,
      int* __restrict__ rowptr, int* __restrict__ cursor){
  int b = blockIdx.x, t = threadIdx.x;
  int i = b*SCHUNK + t;
  if (i < N_NODES){
    int incl = tscan[i] + boff[b];
    rowptr[i+1] = incl;
    cursor[i]   = incl - deg[i];
    if (i == 0) rowptr[0] = 0;
  }
}

__global__ void k_scatter(const int* __restrict__ s0, const int* __restrict__ d0,
                          int* __restrict__ cursor, int* __restrict__ esrc){
  int e = blockIdx.x*blockDim.x + threadIdx.x;
  if (e < N_EDGES){
    int slot = atomicAdd(&cursor[d0[e]], 1);
    esrc[slot] = s0[e];
  }
}

// ---------------- linear: x[N,128] @ w[128,256] col-tiles; 128x128 block tile ----
// grid (8, nb): sel=bx>>1: 0 -> q (fp32, qv stride 512, col 0..255)
//                          1 -> k (FP16 into kh, stride 256)
//                          2 -> v (fp32, qv stride 512, col 256..511)
//                          3 -> skip (fp32 into hbuf, stride 256)
__global__ __launch_bounds__(256) void k_lin(const float* __restrict__ x,
        const float* __restrict__ wq, const float* __restrict__ wk,
        const float* __restrict__ wv, const float* __restrict__ wsk,
        const float* __restrict__ bq, const float* __restrict__ bk,
        const float* __restrict__ bv, const float* __restrict__ bs,
        float* __restrict__ oqv, __half* __restrict__ okh,
        float* __restrict__ oskip){
  __shared__ float xs[128][36];     // row stride 144B (16B-aligned)
  __shared__ float wls[32][128];
  int t  = threadIdx.x;
  int ty = t >> 4, tx = t & 15;
  int n0  = blockIdx.y * 128;
  int bx  = blockIdx.x;
  int sel  = bx >> 1;                  // 0..3 -> q,k,v,skip
  int wcol = (bx & 1) * 128;
  const float* wptr = sel==0 ? wq : sel==1 ? wk : sel==2 ? wv : wsk;
  const float* bptr = sel==0 ? bq : sel==1 ? bk : sel==2 ? bv : bs;

  float acc[8][8];
  #pragma unroll
  for (int i=0;i<8;i++)
    #pragma unroll
    for (int j=0;j<8;j++) acc[i][j] = 0.f;

  for (int k0 = 0; k0 < IN_DIMC; k0 += 32){
    #pragma unroll
    for (int q = 0; q < 4; q++){            // x tile 128x32
      int L = (q*256 + t)*4;
      int row = L >> 5, col = L & 31;
      int gr = n0 + row;
      float4 vv = make_float4(0.f,0.f,0.f,0.f);
      if (gr < N_NODES) vv = *(const float4*)(x + (size_t)gr*IN_DIMC + k0 + col);
      *(float4*)&xs[row][col] = vv;
    }
    #pragma unroll
    for (int q = 0; q < 4; q++){            // w tile 32x128
      int L = (q*256 + t)*4;
      int row = L >> 7, col = L & 127;
      float4 vv = *(const float4*)(wptr + (size_t)(k0+row)*256 + wcol + col);
      *(float4*)&wls[row][col] = vv;
    }
    __syncthreads();
    for (int kk = 0; kk < 32; kk += 4){
      float4 aq[8];
      #pragma unroll
      for (int i=0;i<8;i++) aq[i] = *(const float4*)&xs[ty*8+i][kk];
      #pragma unroll
      for (int u=0;u<4;u++){
        float4 b0v = *(const float4*)&wls[kk+u][tx*4];
        float4 b1v = *(const float4*)&wls[kk+u][64 + tx*4];
        #pragma unroll
        for (int i=0;i<8;i++){
          float a = ((const float*)&aq[i])[u];
          acc[i][0] = fmaf(a,b0v.x,acc[i][0]);
          acc[i][1] = fmaf(a,b0v.y,acc[i][1]);
          acc[i][2] = fmaf(a,b0v.z,acc[i][2]);
          acc[i][3] = fmaf(a,b0v.w,acc[i][3]);
          acc[i][4] = fmaf(a,b1v.x,acc[i][4]);
          acc[i][5] = fmaf(a,b1v.y,acc[i][5]);
          acc[i][6] = fmaf(a,b1v.z,acc[i][6]);
          acc[i][7] = fmaf(a,b1v.w,acc[i][7]);
        }
      }
    }
    __syncthreads();
  }
  #pragma unroll
  for (int i=0;i<8;i++){
    int row = n0 + ty*8 + i;
    if (row >= N_NODES) continue;
    float o[8];
    #pragma unroll
    for (int j=0;j<4;j++){
      o[j]   = acc[i][j]   + bptr[wcol + tx*4 + j];
      o[4+j] = acc[i][4+j] + bptr[wcol + 64 + tx*4 + j];
    }
    if (sel == 1){                         // K -> fp16
      ushort4 h0, h1;
      h0.x = __half_as_ushort(__float2half(o[0]));
      h0.y = __half_as_ushort(__float2half(o[1]));
      h0.z = __half_as_ushort(__float2half(o[2]));
      h0.w = __half_as_ushort(__float2half(o[3]));
      h1.x = __half_as_ushort(__float2half(o[4]));
      h1.y = __half_as_ushort(__float2half(o[5]));
      h1.z = __half_as_ushort(__float2half(o[6]));
      h1.w = __half_as_ushort(__float2half(o[7]));
      *(ushort4*)(okh + (size_t)row*D1 + wcol + tx*4)      = h0;
      *(ushort4*)(okh + (size_t)row*D1 + wcol + 64 + tx*4) = h1;
    } else {
      float* out  = (sel == 3) ? oskip : oqv;
      int ostride = (sel == 3) ? D1 : DQV;
      int col0    = (sel == 0) ? wcol : (sel == 2) ? 256 + wcol : wcol;
      *(float4*)(out + (size_t)row*ostride + col0 + tx*4)      = make_float4(o[0],o[1],o[2],o[3]);
      *(float4*)(out + (size_t)row*ostride + col0 + 64 + tx*4) = make_float4(o[4],o[5],o[6],o[7]);
    }
  }
}

// ---------------- layer-1 fused attention: one wave per node, fp16 K ----------
// lane l owns channels [4l,4l+4). K-row = 512B (fp16), V-row = 1KB (fp32).
// Online softmax; esrc prefetch breaks the per-iteration address chain.
__global__ __launch_bounds__(256) void k_attn1(const float* __restrict__ qv1,
      const __half* __restrict__ kh, const int* __restrict__ rowptr,
      const int* __restrict__ esrc, float* __restrict__ hbuf){
  int wid  = threadIdx.x >> 6;
  int lane = threadIdx.x & 63;
  int n = blockIdx.x*4 + wid;
  if (n >= N_NODES) return;
  int beg = rowptr[n], end = rowptr[n+1];

  float4 q = *(const float4*)(qv1 + (size_t)n*DQV + lane*4);
  const float sc = 0.17677669529663687f;     // 1/sqrt(32), folded into q
  q.x*=sc; q.y*=sc; q.z*=sc; q.w*=sc;

  float m = -INFINITY, s = 0.f;
  float4 acc = make_float4(0.f,0.f,0.f,0.f);
  int src = (beg < end) ? esrc[beg] : 0;
  for (int i = beg; i < end; i++){
    int nsrc = (i+1 < end) ? esrc[i+1] : 0;   // prefetch: breaks addr dependence
    union { uint2 u; __half2 h[2]; } K;
    K.u = *(const uint2*)(kh + (size_t)src*D1 + lane*4);   // 8B fp16 x4
    float4 vv = *(const float4*)(qv1 + (size_t)src*DQV + 256 + lane*4);
    float2 f0 = __half22float2(K.h[0]);
    float2 f1 = __half22float2(K.h[1]);
    float p = q.x*f0.x + q.y*f0.y + q.z*f1.x + q.w*f1.y;
    p += __shfl_xor(p, 1);
    p += __shfl_xor(p, 2);
    p += __shfl_xor(p, 4);     // all 8 lanes of the head group hold the full dot
    float mn = fmaxf(m, p);
    float c  = __expf(m - mn);
    float w  = __expf(p - mn);
    s = s*c + w;
    acc.x = acc.x*c + w*vv.x;
    acc.y = acc.y*c + w*vv.y;
    acc.z = acc.z*c + w*vv.z;
    acc.w = acc.w*c + w*vv.w;
    m = mn;
    src = nsrc;
  }
  float inv = 1.f/(s + 1e-16f);
  size_t o = (size_t)n*D1 + lane*4;
  float4 sk = *(const float4*)(hbuf + o);    // skip term (pre-stored)
  float4 r;
  r.x = acc.x*inv + sk.x;
  r.y = acc.y*inv + sk.y;
  r.z = acc.z*inv + sk.z;
  r.w = acc.w*inv + sk.w;
  r.x = r.x > 0.f ? r.x : expm1f(r.x);       // ELU
  r.y = r.y > 0.f ? r.y : expm1f(r.y);
  r.z = r.z > 0.f ? r.z : expm1f(r.z);
  r.w = r.w > 0.f ? r.w : expm1f(r.w);
  *(float4*)(hbuf + o) = r;
}

// ---------------- layer-2 GEMM: h[N,256] @ [w2q|w2k|w2v|w2s][256,10] ----------------
__global__ __launch_bounds__(256) void k_gemm2(const float* __restrict__ hin,
     const float* __restrict__ wq, const float* __restrict__ wk,
     const float* __restrict__ wv, const float* __restrict__ wsk,
     const float* __restrict__ bq, const float* __restrict__ bk,
     const float* __restrict__ bv, const float* __restrict__ bs,
     float* __restrict__ out){
  __shared__ float hs[64][68];
  __shared__ float wsm[64][40];
  int t = threadIdx.x;
  int r = t >> 2, g = t & 3;
  int n0 = blockIdx.x * 64;
  const float* bsel = g==0 ? bq : g==1 ? bk : g==2 ? bv : bs;
  float acc[10];
  #pragma unroll
  for (int j=0;j<10;j++) acc[j] = 0.f;

  for (int k0 = 0; k0 < D1; k0 += 64){
    #pragma unroll
    for (int q = 0; q < 4; q++){
      int L = (q*256 + t)*4;
      int row = L >> 6, col = L & 63;
      int gr = n0 + row;
      float4 vv = make_float4(0.f,0.f,0.f,0.f);
      if (gr < N_NODES) vv = *(const float4*)(hin + (size_t)gr*D1 + k0 + col);
      *(float4*)&hs[row][col] = vv;
    }
    for (int L = t; L < 64*40; L += 256){
      int row = L/40, cc = L%40;
      int sl = cc/10;
      const float* p = sl==0 ? wq : sl==1 ? wk : sl==2 ? wv : wsk;
      wsm[row][cc] = p[(size_t)(k0+row)*10 + (cc - sl*10)];
    }
    __syncthreads();
    for (int kk = 0; kk < 64; kk++){
      float a = hs[r][kk];
      #pragma unroll
      for (int j=0;j<10;j++) acc[j] = fmaf(a, wsm[kk][g*10+j], acc[j]);
    }
    __syncthreads();
  }
  int gr = n0 + r;
  if (gr < N_NODES){
    #pragma unroll
    for (int j=0;j<10;j++)
      out[(size_t)gr*D2ALL + g*10 + j] = acc[j] + bsel[j];
  }
}

// ---------------- layer-2 fused attention: one wave per node ----------------
__global__ __launch_bounds__(256) void k_agg2(const float* __restrict__ qkvs2,
    const int* __restrict__ rowptr, const int* __restrict__ esrc,
    float* __restrict__ out){
  int wid  = threadIdx.x >> 6;
  int lane = threadIdx.x & 63;
  int n = blockIdx.x*4 + wid;
  if (n >= N_NODES) return;
  int beg = rowptr[n], end = rowptr[n+1];

  float qv[10];
  #pragma unroll
  for (int j=0;j<10;j++) qv[j] = qkvs2[(size_t)n*D2ALL + j];

  float m = -INFINITY, s = 0.f;
  float acc[10];
  #pragma unroll
  for (int j=0;j<10;j++) acc[j] = 0.f;

  for (int base = beg; base < end; base += 64){
    int i  = base + lane;
    int ic = i < end ? i : end-1;
    int src = esrc[ic];
    const float* kp = qkvs2 + (size_t)src*D2ALL + 10;
    const float* vp = qkvs2 + (size_t)src*D2ALL + 20;
    float d = 0.f;
    #pragma unroll
    for (int j=0;j<10;j++) d = fmaf(qv[j], kp[j], d);
    float sd = (i < end) ? d * 0.31622776601683794f : -INFINITY;
    float vvv[10];
    #pragma unroll
    for (int j=0;j<10;j++) vvv[j] = vp[j];
    float cm = sd;
    #pragma unroll
    for (int off = 1; off < 64; off <<= 1) cm = fmaxf(cm, __shfl_xor(cm, off));
    float mn = fmaxf(m, cm);
    float c  = __expf(m - mn);
    float w  = (i < end) ? __expf(sd - mn) : 0.f;
    float ws = w;
    #pragma unroll
    for (int off = 1; off < 64; off <<= 1) ws += __shfl_xor(ws, off);
    s = s*c + ws;
    #pragma unroll
    for (int j=0;j<10;j++){
      float aj = w * vvv[j];
      #pragma unroll
      for (int off = 1; off < 64; off <<= 1) aj += __shfl_xor(aj, off);
      acc[j] = acc[j]*c + aj;
    }
    m = mn;
  }
  if (lane == 0){
    float inv = 1.f/(s + 1e-16f);
    const float* sp = qkvs2 + (size_t)n*D2ALL + 30;
    #pragma unroll
    for (int j=0;j<10;j++) out[(size_t)n*10 + j] = acc[j]*inv + sp[j];
  }
}

static inline size_t align256(size_t x){ return (x + 255) & ~(size_t)255; }

extern "C" void kernel_launch(void* const* d_in, const int* in_sizes, int n_in,
                              void* d_out, int out_size, void* d_ws, size_t ws_size,
                              hipStream_t stream) {
  const float* x   = (const float*)d_in[0];
  const int*   eiw = (const int*)d_in[1];
  const float* w1q=(const float*)d_in[2],  *b1q=(const float*)d_in[3];
  const float* w1k=(const float*)d_in[4],  *b1k=(const float*)d_in[5];
  const float* w1v=(const float*)d_in[6],  *b1v=(const float*)d_in[7];
  const float* w1s=(const float*)d_in[8],  *b1s=(const float*)d_in[9];
  const float* w2q=(const float*)d_in[10], *b2q=(const float*)d_in[11];
  const float* w2k=(const float*)d_in[12], *b2k=(const float*)d_in[13];
  const float* w2v=(const float*)d_in[14], *b2v=(const float*)d_in[15];
  const float* w2s=(const float*)d_in[16], *b2s=(const float*)d_in[17];

  // ---- workspace layout (aliased; peak ~182.6 MB) ----
  const size_t offRow  = 0;
  const size_t offEsrc = align256((size_t)(N_NODES+1)*4);          // rowptr
  const size_t offHbuf = offEsrc + align256((size_t)N_EDGES*4);    // esrc
  const size_t offR    = offHbuf + (size_t)N_NODES*D1*4;           // hbuf
  const size_t offKh   = offR    + (size_t)N_NODES*DQV*4;          // qv region
  const size_t REQ     = offKh   + (size_t)N_NODES*D1*2;           // fp16 k

  if (ws_size < REQ){   // diagnostic: clean wrong-answer instead of OOB crash
    k_zero<<<(out_size+255)/256, 256, 0, stream>>>((float*)d_out, out_size);
    return;
  }

  char* base = (char*)d_ws;
  int*   rowptr = (int*)(base + offRow);
  int*   esrc   = (int*)(base + offEsrc);
  float* hbuf   = (float*)(base + offHbuf);
  float* qv1    = (float*)(base + offR);
  __half* kh    = (__half*)(base + offKh);
  // CSR temps alias the qv region (dead before k_lin writes it)
  size_t co = offR;
  int* deg    = (int*)(base + co); co += align256((size_t)N_NODES*4);
  int* cursor = (int*)(base + co); co += align256((size_t)N_NODES*4);
  int* tscan  = (int*)(base + co); co += align256((size_t)N_NODES*4);
  int* s0     = (int*)(base + co); co += align256((size_t)N_EDGES*4);
  int* d0     = (int*)(base + co); co += align256((size_t)N_EDGES*4);
  int* bsum   = (int*)(base + co); co += align256((size_t)NCHUNK*4);
  int* boff   = (int*)(base + co);
  // layer-2 buffer aliases the qv region (dead after k_attn1)
  float* qkvs2  = (float*)(base + offR);

  hipMemsetAsync(deg, 0, (size_t)N_NODES*4, stream);
  k_edges <<<(N_EDGES+255)/256, 256, 0, stream>>>(eiw, s0, d0, deg);
  k_scanA <<<NCHUNK, 1024, 0, stream>>>(deg, tscan, bsum);
  k_scanB <<<1, 64, 0, stream>>>(bsum, boff);
  k_scanC <<<NCHUNK, 1024, 0, stream>>>(deg, tscan, boff, rowptr, cursor);
  k_scatter<<<(N_EDGES+255)/256, 256, 0, stream>>>(s0, d0, cursor, esrc);

  k_lin<<<dim3(8, (N_NODES+127)/128), 256, 0, stream>>>(
      x, w1q,w1k,w1v,w1s, b1q,b1k,b1v,b1s, qv1, kh, hbuf);  // q|v fp32, k fp16, skip
  k_attn1<<<(N_NODES+3)/4, 256, 0, stream>>>(qv1, kh, rowptr, esrc, hbuf);

  k_gemm2<<<(N_NODES+63)/64, 256, 0, stream>>>(
      hbuf, w2q,w2k,w2v,w2s, b2q,b2k,b2v,b2s, qkvs2);
  k_agg2<<<(N_NODES+3)/4, 256, 0, stream>>>(qkvs2, rowptr, esrc, (float*)d_out);
}

// Round 16
// 565.318 us; speedup vs baseline: 1.6138x; 1.3716x over previous
//
#include <hip/hip_runtime.h>
#include <hip/hip_fp16.h>
#include <math.h>

#define N_NODES 50000
#define N_EDGES 800000
#define IN_DIMC 128
#define D1 256      // heads*hid (layer-1 width; q/k/v/skip each this wide)
#define D2P 64      // layer-2 qkvs padded stride: q@0, k@16, v@32, s@48
#define SCHUNK 1024
#define NCHUNK ((N_NODES + SCHUNK - 1) / SCHUNK)   // 49

// ---------------- diagnostic fallback ----------------
__global__ void k_zero(float* __restrict__ out, int n){
  int i = blockIdx.x*blockDim.x + threadIdx.x;
  if (i < n) out[i] = 0.f;
}

// ---------------- edge decode + degree count (fused) ----------------
__global__ void k_edges(const int* __restrict__ w, int* __restrict__ s0,
                        int* __restrict__ d0, int* __restrict__ deg){
  __shared__ int is64_s;
  if (threadIdx.x == 0){
    int acc = 0;
    #pragma unroll
    for (int j = 0; j < 17; j++) acc |= w[2*j+1];   // int64 hi-words are 0 (ids<50000)
    is64_s = (acc == 0);
  }
  __syncthreads();
  bool is64 = is64_s;
  int e = blockIdx.x*blockDim.x + threadIdx.x;
  if (e < N_EDGES){
    int s, d;
    if (is64){ s = w[2*e];  d = w[2*(N_EDGES + e)]; }
    else     { s = w[e];    d = w[N_EDGES + e];     }
    s0[e] = s;
    d0[e] = d;
    atomicAdd(&deg[d], 1);
  }
}

// ---------------- parallel 3-phase scan over deg[50000] ----------------
__global__ __launch_bounds__(1024) void k_scanA(const int* __restrict__ deg,
      int* __restrict__ tscan, int* __restrict__ bsum){
  __shared__ int wsum[16];
  int b = blockIdx.x, t = threadIdx.x;
  int w = t >> 6, lane = t & 63;
  int i = b*SCHUNK + t;
  int v = (i < N_NODES) ? deg[i] : 0;
  int s = v;
  #pragma unroll
  for (int off = 1; off < 64; off <<= 1){
    int u = __shfl_up(s, off);
    if (lane >= off) s += u;
  }
  if (lane == 63) wsum[w] = s;
  __syncthreads();
  if (w == 0 && lane < 16){
    int ws = wsum[lane];
    #pragma unroll
    for (int off = 1; off < 16; off <<= 1){
      int u = __shfl_up(ws, off);
      if (lane >= off) ws += u;
    }
    wsum[lane] = ws;
  }
  __syncthreads();
  int incl = ((w == 0) ? 0 : wsum[w-1]) + s;   // block-inclusive prefix
  if (i < N_NODES) tscan[i] = incl;
  if (t == 1023) bsum[b] = incl;               // block total
}

__global__ void k_scanB(const int* __restrict__ bsum, int* __restrict__ boff){
  int lane = threadIdx.x;                      // 64 threads, 1 block
  int v = (lane < NCHUNK) ? bsum[lane] : 0;
  int s = v;
  #pragma unroll
  for (int off = 1; off < 64; off <<= 1){
    int u = __shfl_up(s, off);
    if (lane >= off) s += u;
  }
  if (lane < NCHUNK) boff[lane] = s - v;       // exclusive block offset
}

__global__ __launch_bounds__(1024) void k_scanC(const int* __restrict__ deg,
      const int* __restrict__ tscan, const int* __restrict__ boff,
      int* __restrict__ rowptr, int* __restrict__ cursor){
  int b = blockIdx.x, t = threadIdx.x;
  int i = b*SCHUNK + t;
  if (i < N_NODES){
    int incl = tscan[i] + boff[b];
    rowptr[i+1] = incl;
    cursor[i]   = incl - deg[i];
    if (i == 0) rowptr[0] = 0;
  }
}

__global__ void k_scatter(const int* __restrict__ s0, const int* __restrict__ d0,
                          int* __restrict__ cursor, int* __restrict__ esrc){
  int e = blockIdx.x*blockDim.x + threadIdx.x;
  if (e < N_EDGES){
    int slot = atomicAdd(&cursor[d0[e]], 1);
    esrc[slot] = s0[e];
  }
}

// ---------------- linear: x[N,128] @ w[128,256] col-tiles; 128x128 block tile ----
// grid (8, nb): sel=bx>>1: 0 -> q fp32 (oq, stride 256)
//                          1 -> k fp16 (okh) ; 2 -> v fp16 (ovh)
//                          3 -> skip fp32 (oskip)
__global__ __launch_bounds__(256) void k_lin(const float* __restrict__ x,
        const float* __restrict__ wq, const float* __restrict__ wk,
        const float* __restrict__ wv, const float* __restrict__ wsk,
        const float* __restrict__ bq, const float* __restrict__ bk,
        const float* __restrict__ bv, const float* __restrict__ bs,
        float* __restrict__ oq, __half* __restrict__ okh,
        __half* __restrict__ ovh, float* __restrict__ oskip){
  __shared__ float xs[128][36];     // row stride 144B (16B-aligned)
  __shared__ float wls[32][128];
  int t  = threadIdx.x;
  int ty = t >> 4, tx = t & 15;
  int n0  = blockIdx.y * 128;
  int bx  = blockIdx.x;
  int sel  = bx >> 1;                  // 0..3 -> q,k,v,skip
  int wcol = (bx & 1) * 128;
  const float* wptr = sel==0 ? wq : sel==1 ? wk : sel==2 ? wv : wsk;
  const float* bptr = sel==0 ? bq : sel==1 ? bk : sel==2 ? bv : bs;

  float acc[8][8];
  #pragma unroll
  for (int i=0;i<8;i++)
    #pragma unroll
    for (int j=0;j<8;j++) acc[i][j] = 0.f;

  for (int k0 = 0; k0 < IN_DIMC; k0 += 32){
    #pragma unroll
    for (int q = 0; q < 4; q++){            // x tile 128x32
      int L = (q*256 + t)*4;
      int row = L >> 5, col = L & 31;
      int gr = n0 + row;
      float4 vv = make_float4(0.f,0.f,0.f,0.f);
      if (gr < N_NODES) vv = *(const float4*)(x + (size_t)gr*IN_DIMC + k0 + col);
      *(float4*)&xs[row][col] = vv;
    }
    #pragma unroll
    for (int q = 0; q < 4; q++){            // w tile 32x128
      int L = (q*256 + t)*4;
      int row = L >> 7, col = L & 127;
      float4 vv = *(const float4*)(wptr + (size_t)(k0+row)*256 + wcol + col);
      *(float4*)&wls[row][col] = vv;
    }
    __syncthreads();
    for (int kk = 0; kk < 32; kk += 4){
      float4 aq[8];
      #pragma unroll
      for (int i=0;i<8;i++) aq[i] = *(const float4*)&xs[ty*8+i][kk];
      #pragma unroll
      for (int u=0;u<4;u++){
        float4 b0v = *(const float4*)&wls[kk+u][tx*4];
        float4 b1v = *(const float4*)&wls[kk+u][64 + tx*4];
        #pragma unroll
        for (int i=0;i<8;i++){
          float a = ((const float*)&aq[i])[u];
          acc[i][0] = fmaf(a,b0v.x,acc[i][0]);
          acc[i][1] = fmaf(a,b0v.y,acc[i][1]);
          acc[i][2] = fmaf(a,b0v.z,acc[i][2]);
          acc[i][3] = fmaf(a,b0v.w,acc[i][3]);
          acc[i][4] = fmaf(a,b1v.x,acc[i][4]);
          acc[i][5] = fmaf(a,b1v.y,acc[i][5]);
          acc[i][6] = fmaf(a,b1v.z,acc[i][6]);
          acc[i][7] = fmaf(a,b1v.w,acc[i][7]);
        }
      }
    }
    __syncthreads();
  }
  #pragma unroll
  for (int i=0;i<8;i++){
    int row = n0 + ty*8 + i;
    if (row >= N_NODES) continue;
    float o[8];
    #pragma unroll
    for (int j=0;j<4;j++){
      o[j]   = acc[i][j]   + bptr[wcol + tx*4 + j];
      o[4+j] = acc[i][4+j] + bptr[wcol + 64 + tx*4 + j];
    }
    if (sel == 1 || sel == 2){             // K or V -> fp16
      __half* oh = (sel == 1) ? okh : ovh;
      ushort4 h0, h1;
      h0.x = __half_as_ushort(__float2half(o[0]));
      h0.y = __half_as_ushort(__float2half(o[1]));
      h0.z = __half_as_ushort(__float2half(o[2]));
      h0.w = __half_as_ushort(__float2half(o[3]));
      h1.x = __half_as_ushort(__float2half(o[4]));
      h1.y = __half_as_ushort(__float2half(o[5]));
      h1.z = __half_as_ushort(__float2half(o[6]));
      h1.w = __half_as_ushort(__float2half(o[7]));
      *(ushort4*)(oh + (size_t)row*D1 + wcol + tx*4)      = h0;
      *(ushort4*)(oh + (size_t)row*D1 + wcol + 64 + tx*4) = h1;
    } else {
      float* out = (sel == 3) ? oskip : oq;
      *(float4*)(out + (size_t)row*D1 + wcol + tx*4)      = make_float4(o[0],o[1],o[2],o[3]);
      *(float4*)(out + (size_t)row*D1 + wcol + 64 + tx*4) = make_float4(o[4],o[5],o[6],o[7]);
    }
  }
}

// ---------------- layer-1 fused attention: one wave per node, fp16 K+V --------
// lane l owns channels [4l,4l+4). K-row = 512B, V-row = 512B (both fp16).
__global__ __launch_bounds__(256) void k_attn1(const float* __restrict__ q1,
      const __half* __restrict__ kh, const __half* __restrict__ vh,
      const int* __restrict__ rowptr, const int* __restrict__ esrc,
      float* __restrict__ hbuf){
  int wid  = threadIdx.x >> 6;
  int lane = threadIdx.x & 63;
  int n = blockIdx.x*4 + wid;
  if (n >= N_NODES) return;
  int beg = rowptr[n], end = rowptr[n+1];

  float4 q = *(const float4*)(q1 + (size_t)n*D1 + lane*4);
  const float sc = 0.17677669529663687f;     // 1/sqrt(32), folded into q
  q.x*=sc; q.y*=sc; q.z*=sc; q.w*=sc;

  float m = -INFINITY, s = 0.f;
  float4 acc = make_float4(0.f,0.f,0.f,0.f);
  int src = (beg < end) ? esrc[beg] : 0;
  for (int i = beg; i < end; i++){
    int nsrc = (i+1 < end) ? esrc[i+1] : 0;   // prefetch: breaks addr dependence
    union { uint2 u; __half2 h[2]; } K, V;
    K.u = *(const uint2*)(kh + (size_t)src*D1 + lane*4);
    V.u = *(const uint2*)(vh + (size_t)src*D1 + lane*4);
    float2 k0 = __half22float2(K.h[0]);
    float2 k1 = __half22float2(K.h[1]);
    float2 v0 = __half22float2(V.h[0]);
    float2 v1 = __half22float2(V.h[1]);
    float p = q.x*k0.x + q.y*k0.y + q.z*k1.x + q.w*k1.y;
    p += __shfl_xor(p, 1);
    p += __shfl_xor(p, 2);
    p += __shfl_xor(p, 4);     // all 8 lanes of the head group hold the full dot
    float mn = fmaxf(m, p);
    float c  = __expf(m - mn);
    float w  = __expf(p - mn);
    s = s*c + w;
    acc.x = acc.x*c + w*v0.x;
    acc.y = acc.y*c + w*v0.y;
    acc.z = acc.z*c + w*v1.x;
    acc.w = acc.w*c + w*v1.y;
    m = mn;
    src = nsrc;
  }
  float inv = 1.f/(s + 1e-16f);
  size_t o = (size_t)n*D1 + lane*4;
  float4 sk = *(const float4*)(hbuf + o);    // skip term (pre-stored)
  float4 r;
  r.x = acc.x*inv + sk.x;
  r.y = acc.y*inv + sk.y;
  r.z = acc.z*inv + sk.z;
  r.w = acc.w*inv + sk.w;
  r.x = r.x > 0.f ? r.x : expm1f(r.x);       // ELU
  r.y = r.y > 0.f ? r.y : expm1f(r.y);
  r.z = r.z > 0.f ? r.z : expm1f(r.z);
  r.w = r.w > 0.f ? r.w : expm1f(r.w);
  *(float4*)(hbuf + o) = r;
}

// ---------------- layer-2 GEMM: h[N,256] @ [w2q|w2k|w2v|w2s][256,10] ----------
// Weights transposed in LDS [40][260] (b128 reads); h via direct float4 global
// (L3-resident); output padded stride 64 with aligned vector stores.
__global__ __launch_bounds__(256) void k_gemm2(const float* __restrict__ hin,
     const float* __restrict__ wq, const float* __restrict__ wk,
     const float* __restrict__ wv, const float* __restrict__ wsk,
     const float* __restrict__ bq, const float* __restrict__ bk,
     const float* __restrict__ bv, const float* __restrict__ bs,
     float* __restrict__ out){
  __shared__ float wT[40][260];    // wT[cc][k]; row stride 1040B
  __shared__ float bsm[40];
  int t = threadIdx.x;
  for (int L = t; L < 40*256; L += 256){
    int cc = L >> 8, k = L & 255;         // cc = L/256, k = L%256
    int sl = cc / 10;
    const float* p = sl==0 ? wq : sl==1 ? wk : sl==2 ? wv : wsk;
    wT[cc][k] = p[(size_t)k*10 + cc - sl*10];
  }
  if (t < 40){
    int sl = t / 10;
    const float* bp = sl==0 ? bq : sl==1 ? bk : sl==2 ? bv : bs;
    bsm[t] = bp[t - sl*10];
  }
  __syncthreads();
  int r = t >> 2, g = t & 3;             // node-in-block, weight-group
  int n = blockIdx.x*64 + r;
  if (n >= N_NODES) return;
  float acc[10];
  #pragma unroll
  for (int j=0;j<10;j++) acc[j] = 0.f;
  const float* hp = hin + (size_t)n*D1;
  for (int k = 0; k < D1; k += 4){
    float4 hv = *(const float4*)(hp + k);
    #pragma unroll
    for (int j=0;j<10;j++){
      float4 wv4 = *(const float4*)&wT[g*10+j][k];
      acc[j] = fmaf(hv.x, wv4.x, acc[j]);
      acc[j] = fmaf(hv.y, wv4.y, acc[j]);
      acc[j] = fmaf(hv.z, wv4.z, acc[j]);
      acc[j] = fmaf(hv.w, wv4.w, acc[j]);
    }
  }
  float* op = out + (size_t)n*D2P + g*16;
  *(float4*)(op + 0) = make_float4(acc[0]+bsm[g*10+0], acc[1]+bsm[g*10+1],
                                   acc[2]+bsm[g*10+2], acc[3]+bsm[g*10+3]);
  *(float4*)(op + 4) = make_float4(acc[4]+bsm[g*10+4], acc[5]+bsm[g*10+5],
                                   acc[6]+bsm[g*10+6], acc[7]+bsm[g*10+7]);
  *(float2*)(op + 8) = make_float2(acc[8]+bsm[g*10+8], acc[9]+bsm[g*10+9]);
}

// ---------------- layer-2 fused attention: one wave per node ----------------
// qkvs2 padded stride 64: q@0, k@16, v@32, s@48. Predicated loads (no clamp).
__global__ __launch_bounds__(256) void k_agg2(const float* __restrict__ qkvs2,
    const int* __restrict__ rowptr, const int* __restrict__ esrc,
    float* __restrict__ out){
  int wid  = threadIdx.x >> 6;
  int lane = threadIdx.x & 63;
  int n = blockIdx.x*4 + wid;
  if (n >= N_NODES) return;
  int beg = rowptr[n], end = rowptr[n+1];

  float qv[10];
  #pragma unroll
  for (int j=0;j<10;j++) qv[j] = qkvs2[(size_t)n*D2P + j];

  float m = -INFINITY, s = 0.f;
  float acc[10];
  #pragma unroll
  for (int j=0;j<10;j++) acc[j] = 0.f;

  for (int base = beg; base < end; base += 64){
    int i  = base + lane;
    bool act = (i < end);
    float sd = -INFINITY;
    float vvv[10];
    #pragma unroll
    for (int j=0;j<10;j++) vvv[j] = 0.f;
    if (act){
      int src = esrc[i];
      const float* kp = qkvs2 + (size_t)src*D2P + 16;
      const float* vp = qkvs2 + (size_t)src*D2P + 32;
      float d = 0.f;
      #pragma unroll
      for (int j=0;j<10;j++) d = fmaf(qv[j], kp[j], d);
      sd = d * 0.31622776601683794f;   // 1/sqrt(10)
      #pragma unroll
      for (int j=0;j<10;j++) vvv[j] = vp[j];
    }
    float cm = sd;
    #pragma unroll
    for (int off = 1; off < 64; off <<= 1) cm = fmaxf(cm, __shfl_xor(cm, off));
    float mn = fmaxf(m, cm);
    float c  = __expf(m - mn);             // 0 on first chunk (m=-inf)
    float w  = act ? __expf(sd - mn) : 0.f;
    float ws = w;
    #pragma unroll
    for (int off = 1; off < 64; off <<= 1) ws += __shfl_xor(ws, off);
    s = s*c + ws;
    #pragma unroll
    for (int j=0;j<10;j++){
      float aj = w * vvv[j];
      #pragma unroll
      for (int off = 1; off < 64; off <<= 1) aj += __shfl_xor(aj, off);
      acc[j] = acc[j]*c + aj;
    }
    m = mn;
  }
  if (lane == 0){
    float inv = 1.f/(s + 1e-16f);
    const float* sp = qkvs2 + (size_t)n*D2P + 48;
    #pragma unroll
    for (int j=0;j<10;j++) out[(size_t)n*10 + j] = acc[j]*inv + sp[j];
  }
}

static inline size_t align256(size_t x){ return (x + 255) & ~(size_t)255; }

extern "C" void kernel_launch(void* const* d_in, const int* in_sizes, int n_in,
                              void* d_out, int out_size, void* d_ws, size_t ws_size,
                              hipStream_t stream) {
  const float* x   = (const float*)d_in[0];
  const int*   eiw = (const int*)d_in[1];
  const float* w1q=(const float*)d_in[2],  *b1q=(const float*)d_in[3];
  const float* w1k=(const float*)d_in[4],  *b1k=(const float*)d_in[5];
  const float* w1v=(const float*)d_in[6],  *b1v=(const float*)d_in[7];
  const float* w1s=(const float*)d_in[8],  *b1s=(const float*)d_in[9];
  const float* w2q=(const float*)d_in[10], *b2q=(const float*)d_in[11];
  const float* w2k=(const float*)d_in[12], *b2k=(const float*)d_in[13];
  const float* w2v=(const float*)d_in[14], *b2v=(const float*)d_in[15];
  const float* w2s=(const float*)d_in[16], *b2s=(const float*)d_in[17];

  // ---- workspace layout: FULLY NON-ALIASED (peak ~176.8 MB) ----
  const size_t offRow  = 0;
  const size_t offEsrc = align256((size_t)(N_NODES+1)*4);          // rowptr
  const size_t offHbuf = offEsrc + align256((size_t)N_EDGES*4);    // esrc
  const size_t offQ    = offHbuf + (size_t)N_NODES*D1*4;           // hbuf
  const size_t offKh   = offQ    + (size_t)N_NODES*D1*4;           // q fp32
  const size_t offVh   = offKh   + (size_t)N_NODES*D1*2;           // k fp16
  const size_t offQk2  = offVh   + (size_t)N_NODES*D1*2;           // v fp16
  const size_t offTmp  = offQk2  + (size_t)N_NODES*D2P*4;          // qkvs2
  const size_t szTmp   = 3*align256((size_t)N_NODES*4)
                       + 2*align256((size_t)N_EDGES*4)
                       + 2*align256((size_t)NCHUNK*4);
  const size_t REQ     = offTmp + szTmp;

  if (ws_size < REQ){   // diagnostic: clean wrong-answer instead of OOB crash
    k_zero<<<(out_size+255)/256, 256, 0, stream>>>((float*)d_out, out_size);
    return;
  }

  char* base = (char*)d_ws;
  int*    rowptr = (int*)(base + offRow);
  int*    esrc   = (int*)(base + offEsrc);
  float*  hbuf   = (float*)(base + offHbuf);
  float*  q1     = (float*)(base + offQ);
  __half* kh     = (__half*)(base + offKh);
  __half* vh     = (__half*)(base + offVh);
  float*  qkvs2  = (float*)(base + offQk2);
  size_t co = offTmp;                        // dedicated CSR temps (no aliasing)
  int* deg    = (int*)(base + co); co += align256((size_t)N_NODES*4);
  int* cursor = (int*)(base + co); co += align256((size_t)N_NODES*4);
  int* tscan  = (int*)(base + co); co += align256((size_t)N_NODES*4);
  int* s0     = (int*)(base + co); co += align256((size_t)N_EDGES*4);
  int* d0     = (int*)(base + co); co += align256((size_t)N_EDGES*4);
  int* bsum   = (int*)(base + co); co += align256((size_t)NCHUNK*4);
  int* boff   = (int*)(base + co);

  hipMemsetAsync(deg, 0, (size_t)N_NODES*4, stream);
  k_edges <<<(N_EDGES+255)/256, 256, 0, stream>>>(eiw, s0, d0, deg);
  k_scanA <<<NCHUNK, 1024, 0, stream>>>(deg, tscan, bsum);
  k_scanB <<<1, 64, 0, stream>>>(bsum, boff);
  k_scanC <<<NCHUNK, 1024, 0, stream>>>(deg, tscan, boff, rowptr, cursor);
  k_scatter<<<(N_EDGES+255)/256, 256, 0, stream>>>(s0, d0, cursor, esrc);

  k_lin<<<dim3(8, (N_NODES+127)/128), 256, 0, stream>>>(
      x, w1q,w1k,w1v,w1s, b1q,b1k,b1v,b1s, q1, kh, vh, hbuf);
  k_attn1<<<(N_NODES+3)/4, 256, 0, stream>>>(q1, kh, vh, rowptr, esrc, hbuf);

  k_gemm2<<<(N_NODES+63)/64, 256, 0, stream>>>(
      hbuf, w2q,w2k,w2v,w2s, b2q,b2k,b2v,b2s, qkvs2);
  k_agg2<<<(N_NODES+3)/4, 256, 0, stream>>>(qkvs2, rowptr, esrc, (float*)d_out);
}